// Round 2
// baseline (271.276 us; speedup 1.0000x reference)
//
#include <hip/hip_runtime.h>
#include <stdint.h>
#include <stddef.h>

#define DEVI __device__ __forceinline__

typedef __attribute__((ext_vector_type(8)))  short bf16x8;
typedef __attribute__((ext_vector_type(4)))  float f32x4;
typedef __attribute__((ext_vector_type(16))) float f32x16;

DEVI unsigned short f2bf(float f) {
    union { float f; unsigned u; } v; v.f = f;
    return (unsigned short)((v.u + 0x7FFFu + ((v.u >> 16) & 1u)) >> 16);
}
DEVI f32x4 zero4() { f32x4 z; z[0] = z[1] = z[2] = z[3] = 0.f; return z; }
DEVI f32x16 zero16() {
    f32x16 z;
#pragma unroll
    for (int i = 0; i < 16; ++i) z[i] = 0.f;
    return z;
}

// B fragment (16x16x32): rows c0..c0+7 of X (row stride 256 floats), column p
DEVI bf16x8 ldb(const float* __restrict__ xg, int c0, int p) {
    bf16x8 b;
#pragma unroll
    for (int j = 0; j < 8; ++j) b[j] = (short)f2bf(xg[(size_t)(c0 + j) * 256 + p]);
    return b;
}
// A fragment: W[row][c0..c0+7], contiguous
DEVI bf16x8 lda_w(const float* __restrict__ W, int row, int c0) {
    bf16x8 a;
#pragma unroll
    for (int j = 0; j < 8; ++j) a[j] = (short)f2bf(W[row * 64 + c0 + j]);
    return a;
}

// ---------------------------------------------------------------------------
// ws layout:
//   qbf [1024][64][256] bf16 @ 0          (33,554,432 B)
//   kbf [2048][64][256] bf16 @ 33554432   (67,108,864 B)
//   vbf [2048][64][256] bf16 @ 100663296  (67,108,864 B)  (natural layout now)
//   partial [4][4096][128] f32 @ 167772160 (8,388,608 B)
//   pbf [4096][128] bf16 @ 176160768      (1,048,576 B)
// ---------------------------------------------------------------------------

// ============================ proj q ============================
// block = one image, 256 threads, no LDS. B-frags direct from global fp32.
__global__ __launch_bounds__(256) void proj_q_kernel(
    const float* __restrict__ qq, const float* __restrict__ Wq,
    const float* __restrict__ bq, unsigned short* __restrict__ qbf)
{
    const int tid = threadIdx.x;
    const int w = tid >> 6, lane = tid & 63;
    const int l15 = lane & 15, lg = lane >> 4;
    const int n = blockIdx.x;
    const float* xg = qq + (size_t)n * 16384;

    bf16x8 af[4][2];
#pragma unroll
    for (int ot = 0; ot < 4; ++ot) {
        af[ot][0] = lda_w(Wq, ot * 16 + l15, lg * 8);
        af[ot][1] = lda_w(Wq, ot * 16 + l15, 32 + lg * 8);
    }

#pragma unroll
    for (int pt = 0; pt < 4; ++pt) {
        const int p = w * 64 + pt * 16 + l15;
        bf16x8 b0 = ldb(xg, lg * 8, p);
        bf16x8 b1 = ldb(xg, 32 + lg * 8, p);
#pragma unroll
        for (int ot = 0; ot < 4; ++ot) {
            f32x4 acc = zero4();
            acc = __builtin_amdgcn_mfma_f32_16x16x32_bf16(af[ot][0], b0, acc, 0, 0, 0);
            acc = __builtin_amdgcn_mfma_f32_16x16x32_bf16(af[ot][1], b1, acc, 0, 0, 0);
#pragma unroll
            for (int r = 0; r < 4; ++r) {
                int o = ot * 16 + lg * 4 + r;
                qbf[((size_t)n * 64 + o) * 256 + p] = f2bf(acc[r] + bq[o]);
            }
        }
    }
}

// ============================ proj k + v ============================
// one X read feeds both k and v; both outputs natural (coalesced-ish) layout
__global__ __launch_bounds__(256) void proj_kv_kernel(
    const float* __restrict__ kv, const float* __restrict__ Wk,
    const float* __restrict__ bk, const float* __restrict__ Wv,
    const float* __restrict__ bv, unsigned short* __restrict__ kbf,
    unsigned short* __restrict__ vbf)
{
    const int tid = threadIdx.x;
    const int w = tid >> 6, lane = tid & 63;
    const int l15 = lane & 15, lg = lane >> 4;
    const int n = blockIdx.x;
    const float* xg = kv + (size_t)n * 16384;

    bf16x8 afk[4][2], afv[4][2];
#pragma unroll
    for (int ot = 0; ot < 4; ++ot) {
        afk[ot][0] = lda_w(Wk, ot * 16 + l15, lg * 8);
        afk[ot][1] = lda_w(Wk, ot * 16 + l15, 32 + lg * 8);
        afv[ot][0] = lda_w(Wv, ot * 16 + l15, lg * 8);
        afv[ot][1] = lda_w(Wv, ot * 16 + l15, 32 + lg * 8);
    }

#pragma unroll
    for (int pt = 0; pt < 4; ++pt) {
        const int p = w * 64 + pt * 16 + l15;
        bf16x8 b0 = ldb(xg, lg * 8, p);
        bf16x8 b1 = ldb(xg, 32 + lg * 8, p);
#pragma unroll
        for (int ot = 0; ot < 4; ++ot) {
            f32x4 acck = zero4(), accv = zero4();
            acck = __builtin_amdgcn_mfma_f32_16x16x32_bf16(afk[ot][0], b0, acck, 0, 0, 0);
            acck = __builtin_amdgcn_mfma_f32_16x16x32_bf16(afk[ot][1], b1, acck, 0, 0, 0);
            accv = __builtin_amdgcn_mfma_f32_16x16x32_bf16(afv[ot][0], b0, accv, 0, 0, 0);
            accv = __builtin_amdgcn_mfma_f32_16x16x32_bf16(afv[ot][1], b1, accv, 0, 0, 0);
#pragma unroll
            for (int r = 0; r < 4; ++r) {
                int o = ot * 16 + lg * 4 + r;
                kbf[((size_t)n * 64 + o) * 256 + p] = f2bf(acck[r] + bk[o]);
                vbf[((size_t)n * 64 + o) * 256 + p] = f2bf(accv[r] + bv[o]);
            }
        }
    }
}

// ============================ sim (Q.K^T partials) ============================
// grid 1024 = bh(64) x kq-split(4) x K-split(4); block 128 (2 waves, t-halves of 64)
// XCD-chunked mapping: the 4 kq-siblings sharing a K-chunk land on one XCD.
__global__ __launch_bounds__(128) void sim_kernel(
    const unsigned short* __restrict__ qbf, const unsigned short* __restrict__ kbf,
    float* __restrict__ partial)
{
    const int tid = threadIdx.x;
    const int w = tid >> 6, lane = tid & 63;
    const int l15 = lane & 15, lg = lane >> 4;
    const int bid = blockIdx.x;
    const int l = (bid & 7) * 128 + (bid >> 3);   // same-XCD blocks get consecutive l
    const int kq4 = l & 3, ks = (l >> 2) & 3, bh = l >> 4;
    const int b = bh >> 2, h = bh & 3;

    const unsigned short* qp = qbf + ((size_t)b * 64 + kq4 * 16 + l15) * 16384
                                   + h * 4096 + ks * 1024 + lg * 8;
    const unsigned short* kp = kbf + ((size_t)b * 128 + w * 64 + l15) * 16384
                                   + h * 4096 + ks * 1024 + lg * 8;

    f32x4 acc[4];
#pragma unroll
    for (int tt = 0; tt < 4; ++tt) acc[tt] = zero4();

    for (int kk = 0; kk < 32; ++kk) {
        bf16x8 a = *(const bf16x8*)(qp + kk * 32);
#pragma unroll
        for (int tt = 0; tt < 4; ++tt) {
            bf16x8 bfr = *(const bf16x8*)(kp + (size_t)tt * 16 * 16384 + kk * 32);
            acc[tt] = __builtin_amdgcn_mfma_f32_16x16x32_bf16(a, bfr, acc[tt], 0, 0, 0);
        }
    }

    float* pb = partial + ((size_t)ks * 4096 + (size_t)bh * 64 + kq4 * 16) * 128 + w * 64;
#pragma unroll
    for (int tt = 0; tt < 4; ++tt)
#pragma unroll
        for (int r = 0; r < 4; ++r)
            pb[(lg * 4 + r) * 128 + tt * 16 + l15] = acc[tt][r];
}

// ============================ softmax ============================
__global__ __launch_bounds__(256) void softmax_kernel(
    const float* __restrict__ partial, float* __restrict__ sim_out,
    unsigned short* __restrict__ pbf)
{
    const int tid = threadIdx.x;
    const int w = tid >> 6, lane = tid & 63;
    const int row = blockIdx.x * 4 + w;

    float x0 = 0.f, x1 = 0.f;
#pragma unroll
    for (int s = 0; s < 4; ++s) {
        x0 += partial[((size_t)s * 4096 + row) * 128 + lane];
        x1 += partial[((size_t)s * 4096 + row) * 128 + 64 + lane];
    }
    const float scale = 1.0f / 64.0f;
    x0 *= scale; x1 *= scale;
    float m = fmaxf(x0, x1);
#pragma unroll
    for (int off = 32; off; off >>= 1) m = fmaxf(m, __shfl_xor(m, off));
    float e0 = __expf(x0 - m), e1 = __expf(x1 - m);
    float s = e0 + e1;
#pragma unroll
    for (int off = 32; off; off >>= 1) s += __shfl_xor(s, off);
    float inv = 1.0f / s;
    float p0 = e0 * inv, p1 = e1 * inv;
    sim_out[(size_t)row * 128 + lane]      = p0;
    sim_out[(size_t)row * 128 + 64 + lane] = p1;
    pbf[(size_t)row * 128 + lane]      = f2bf(p0);
    pbf[(size_t)row * 128 + 64 + lane] = f2bf(p1);
}

// ============================ PV ============================
// grid 1024 = bh(64) x colblock(16); block 256 (4 waves x 64 cols).
// V consumed in natural layout via scalar u16 loads (transpose-on-read).
__global__ __launch_bounds__(256) void pv_kernel(
    const unsigned short* __restrict__ pbf, const unsigned short* __restrict__ vbf,
    float* __restrict__ outp)
{
    const int tid = threadIdx.x;
    const int w = tid >> 6, lane = tid & 63;
    const int l31 = lane & 31, lh = lane >> 5;
    const int bh = blockIdx.x >> 4, cb = blockIdx.x & 15;
    const int b = bh >> 2, h = bh & 3;
    const int ch = h * 16 + cb;
    const int p0 = w * 64;

    const unsigned short* pb = pbf + (size_t)bh * 64 * 128;
    const unsigned short* vb = vbf + (size_t)b * 128 * 16384 + (size_t)ch * 256;

    f32x16 acc00 = zero16(), acc01 = zero16(), acc10 = zero16(), acc11 = zero16();
    for (int kk = 0; kk < 8; ++kk) {
        const int t0 = kk * 16;
        bf16x8 a0 = *(const bf16x8*)(pb + (size_t)l31 * 128 + t0 + lh * 8);
        bf16x8 a1 = *(const bf16x8*)(pb + (size_t)(l31 + 32) * 128 + t0 + lh * 8);
        bf16x8 b0, b1;
#pragma unroll
        for (int j = 0; j < 8; ++j) {
            const unsigned short* vr = vb + (size_t)(t0 + lh * 8 + j) * 16384;
            b0[j] = (short)vr[p0 + l31];
            b1[j] = (short)vr[p0 + 32 + l31];
        }
        acc00 = __builtin_amdgcn_mfma_f32_32x32x16_bf16(a0, b0, acc00, 0, 0, 0);
        acc01 = __builtin_amdgcn_mfma_f32_32x32x16_bf16(a0, b1, acc01, 0, 0, 0);
        acc10 = __builtin_amdgcn_mfma_f32_32x32x16_bf16(a1, b0, acc10, 0, 0, 0);
        acc11 = __builtin_amdgcn_mfma_f32_32x32x16_bf16(a1, b1, acc11, 0, 0, 0);
    }

    float* ob = outp + (size_t)b * 64 * 16384 + (size_t)ch * 256;
#pragma unroll
    for (int r = 0; r < 16; ++r) {
        int kqr = (r & 3) + 8 * (r >> 2) + 4 * lh;
        ob[(size_t)(kqr)      * 16384 + p0 + l31]      = acc00[r];
        ob[(size_t)(kqr)      * 16384 + p0 + 32 + l31] = acc01[r];
        ob[(size_t)(kqr + 32) * 16384 + p0 + l31]      = acc10[r];
        ob[(size_t)(kqr + 32) * 16384 + p0 + 32 + l31] = acc11[r];
    }
}

// ============================ launch ============================
extern "C" void kernel_launch(void* const* d_in, const int* in_sizes, int n_in,
                              void* d_out, int out_size, void* d_ws, size_t ws_size,
                              hipStream_t stream)
{
    const float* qq = (const float*)d_in[0];
    const float* kv = (const float*)d_in[1];
    const float* Wq = (const float*)d_in[2];
    const float* bq = (const float*)d_in[3];
    const float* Wk = (const float*)d_in[4];
    const float* bk = (const float*)d_in[5];
    const float* Wv = (const float*)d_in[6];
    const float* bv = (const float*)d_in[7];

    float* outp    = (float*)d_out;
    float* sim_out = outp + (size_t)16777216;

    char* ws = (char*)d_ws;
    unsigned short* qbf     = (unsigned short*)(ws);
    unsigned short* kbf     = (unsigned short*)(ws + 33554432);
    unsigned short* vbf     = (unsigned short*)(ws + 100663296);
    float*          partial = (float*)         (ws + 167772160);
    unsigned short* pbf     = (unsigned short*)(ws + 176160768);
    (void)in_sizes; (void)n_in; (void)out_size; (void)ws_size;

    proj_q_kernel <<<dim3(1024), dim3(256), 0, stream>>>(qq, Wq, bq, qbf);
    proj_kv_kernel<<<dim3(2048), dim3(256), 0, stream>>>(kv, Wk, bk, Wv, bv, kbf, vbf);
    sim_kernel    <<<dim3(1024), dim3(128), 0, stream>>>(qbf, kbf, partial);
    softmax_kernel<<<dim3(1024), dim3(256), 0, stream>>>(partial, sim_out, pbf);
    pv_kernel     <<<dim3(1024), dim3(256), 0, stream>>>(pbf, vbf, outp);
}